// Round 4
// baseline (408.150 us; speedup 1.0000x reference)
//
#include <hip/hip_runtime.h>

#define N_NODES 50000
#define N_EDGES 800000
#define SCAN_BLOCKS 196            // ceil(50000/256)
#define N_BUCKETS 782              // ceil(50000/64), 64 nodes per bucket

// ---------------- CSR build ----------------

__global__ __launch_bounds__(256)
void hist_kernel(const int* __restrict__ dst, int* __restrict__ counts) {
    int e = blockIdx.x * blockDim.x + threadIdx.x;
    if (e < N_EDGES) atomicAdd(&counts[dst[e]], 1);
}

__global__ __launch_bounds__(256)
void scan_blocks_kernel(const int* __restrict__ counts, int* __restrict__ partials) {
    __shared__ int buf[256];
    int i = blockIdx.x * 256 + threadIdx.x;
    buf[threadIdx.x] = (i < N_NODES) ? counts[i] : 0;
    __syncthreads();
    for (int off = 128; off > 0; off >>= 1) {
        if (threadIdx.x < off) buf[threadIdx.x] += buf[threadIdx.x + off];
        __syncthreads();
    }
    if (threadIdx.x == 0) partials[blockIdx.x] = buf[0];
}

// Parallel exclusive scan of SCAN_BLOCKS (<=256) partials in one block.
__global__ __launch_bounds__(256)
void scan_top_kernel(int* __restrict__ partials) {
    __shared__ int buf[256];
    int t = threadIdx.x;
    int v = (t < SCAN_BLOCKS) ? partials[t] : 0;
    buf[t] = v;
    __syncthreads();
    for (int off = 1; off < 256; off <<= 1) {
        int add = (t >= off) ? buf[t - off] : 0;
        __syncthreads();
        buf[t] += add;
        __syncthreads();
    }
    if (t < SCAN_BLOCKS) partials[t] = buf[t] - v;   // exclusive
}

__global__ __launch_bounds__(256)
void scan_apply_kernel(const int* __restrict__ counts, const int* __restrict__ offsets,
                       int* __restrict__ row_ptr) {
    __shared__ int buf[256];
    int t = threadIdx.x;
    int i = blockIdx.x * 256 + t;
    int v = (i < N_NODES) ? counts[i] : 0;
    buf[t] = v;
    __syncthreads();
    for (int off = 1; off < 256; off <<= 1) {
        int add = (t >= off) ? buf[t - off] : 0;
        __syncthreads();
        buf[t] += add;
        __syncthreads();
    }
    if (i < N_NODES) row_ptr[i] = offsets[blockIdx.x] + buf[t] - v;  // exclusive
}

// bucket cursors init: bucket b starts at row_ptr[64*b]
__global__ __launch_bounds__(256)
void bucket_cursor_init(const int* __restrict__ row_ptr, int* __restrict__ bcursor) {
    int b = blockIdx.x * blockDim.x + threadIdx.x;
    if (b < N_BUCKETS) bcursor[b] = row_ptr[b * 64];
}

// Pass B: append (dst,src) records into bucketed regions (782 hot write tails).
__global__ __launch_bounds__(256)
void bucket_append(const int* __restrict__ src, const int* __restrict__ dst,
                   int* __restrict__ bcursor, unsigned long long* __restrict__ brec) {
    int e = blockIdx.x * blockDim.x + threadIdx.x;
    if (e < N_EDGES) {
        int s = src[e];
        int d = dst[e];
        int pos = atomicAdd(&bcursor[d >> 6], 1);
        brec[pos] = ((unsigned long long)(unsigned)d << 32) | (unsigned)s;
    }
}

// Pass C: one block per bucket; LDS cursors for its 64 nodes; scatter confined
// to the bucket's contiguous CSR window (L2-resident).
__global__ __launch_bounds__(256)
void bucket_fill(const int* __restrict__ row_ptr,
                 const unsigned long long* __restrict__ brec,
                 int* __restrict__ csr_src) {
    __shared__ int cur[64];
    const int b  = blockIdx.x;
    const int nb = b * 64;
    if (threadIdx.x < 64) {
        int n = nb + threadIdx.x;
        cur[threadIdx.x] = (n < N_NODES) ? row_ptr[n] : N_EDGES;
    }
    const int start = row_ptr[nb];
    const int end   = (b == N_BUCKETS - 1) ? N_EDGES : row_ptr[nb + 64];
    __syncthreads();
    for (int idx = start + (int)threadIdx.x; idx < end; idx += 256) {
        unsigned long long r = brec[idx];
        int d = (int)(r >> 32);
        int s = (int)(unsigned)r;
        int pos = atomicAdd(&cur[d - nb], 1);
        csr_src[pos] = s;
    }
}

// ---------------- Register-tiled fp32 GEMM: C[N,F] = A[N,64] @ [B1|B2] ----------------
template <int F>
__global__ __launch_bounds__(256)
void gemm_cat(const float* __restrict__ A,
              const float* __restrict__ B1,   // [64, F/2]
              const float* __restrict__ B2,   // [64, F/2]
              float* __restrict__ C) {
    constexpr int H = F / 2;
    constexpr int HALVES = F / 64;          // 1 or 2
    __shared__ float As[64][68];            // transposed A tile, padded
    __shared__ float Bs[64][F];

    for (int i = threadIdx.x; i < 64 * H; i += 256) {
        int k = i / H, j = i % H;
        Bs[k][j]     = B1[i];
        Bs[k][j + H] = B2[i];
    }
    const int m0 = blockIdx.x * 64;
    {
        int mloc = threadIdx.x >> 4;          // 0..15
        int k4   = (threadIdx.x & 15) * 4;    // 0..60
#pragma unroll
        for (int it = 0; it < 4; ++it) {
            int m  = mloc + it * 16;
            int gm = m0 + m;
            float4 a = (gm < N_NODES) ? *(const float4*)&A[(size_t)gm * 64 + k4]
                                      : make_float4(0.f, 0.f, 0.f, 0.f);
            As[k4 + 0][m] = a.x; As[k4 + 1][m] = a.y;
            As[k4 + 2][m] = a.z; As[k4 + 3][m] = a.w;
        }
    }
    __syncthreads();

    const int tm  = ((threadIdx.x >> 4) & 3) * 4 + (threadIdx.x >> 6) * 16;  // 0..60
    const int tn4 = (threadIdx.x & 15) * 4;                                   // 0..60

    float acc[4][HALVES][4];
#pragma unroll
    for (int mi = 0; mi < 4; ++mi)
#pragma unroll
        for (int hh = 0; hh < HALVES; ++hh)
#pragma unroll
            for (int ni = 0; ni < 4; ++ni) acc[mi][hh][ni] = 0.f;

#pragma unroll 8
    for (int k = 0; k < 64; ++k) {
        float4 a = *(const float4*)&As[k][tm];
        float4 b[HALVES];
#pragma unroll
        for (int hh = 0; hh < HALVES; ++hh)
            b[hh] = *(const float4*)&Bs[k][tn4 + hh * 64];
        const float am[4] = {a.x, a.y, a.z, a.w};
#pragma unroll
        for (int mi = 0; mi < 4; ++mi) {
#pragma unroll
            for (int hh = 0; hh < HALVES; ++hh) {
                acc[mi][hh][0] += am[mi] * b[hh].x;
                acc[mi][hh][1] += am[mi] * b[hh].y;
                acc[mi][hh][2] += am[mi] * b[hh].z;
                acc[mi][hh][3] += am[mi] * b[hh].w;
            }
        }
    }

#pragma unroll
    for (int mi = 0; mi < 4; ++mi) {
        int gm = m0 + tm + mi;
        if (gm < N_NODES) {
#pragma unroll
            for (int hh = 0; hh < HALVES; ++hh)
                *(float4*)&C[(size_t)gm * F + tn4 + hh * 64] = *(float4*)&acc[mi][hh][0];
        }
    }
}

// ---------------- Gather mean + fused epilogue ----------------
template <int F, bool RELU>
__global__ __launch_bounds__(256)
void gather_epilogue(const float* __restrict__ T,
                     const int* __restrict__ row_ptr, const int* __restrict__ counts,
                     const int* __restrict__ csr_src, const float* __restrict__ bias,
                     float* __restrict__ out) {
    constexpr int LPR = F / 4;
    constexpr int R   = 64 / LPR;
    int wave = (blockIdx.x * blockDim.x + threadIdx.x) >> 6;   // = node id
    int lane = threadIdx.x & 63;
    int r = lane / LPR;
    int c = lane % LPR;
    int v = wave;
    if (v >= N_NODES) return;
    int start = row_ptr[v];
    int cnt   = counts[v];

    float ax = 0.f, ay = 0.f, az = 0.f, aw = 0.f;
    for (int t = r; t < cnt; t += R) {
        int s = csr_src[start + t];
        float4 p = *(const float4*)&T[(size_t)s * (2 * F) + F + c * 4];
        ax += p.x; ay += p.y; az += p.z; aw += p.w;
    }
#pragma unroll
    for (int off = LPR; off < 64; off <<= 1) {
        ax += __shfl_xor(ax, off);
        ay += __shfl_xor(ay, off);
        az += __shfl_xor(az, off);
        aw += __shfl_xor(aw, off);
    }
    if (r == 0) {
        float inv = 1.0f / (float)max(cnt, 1);
        float4 self = *(const float4*)&T[(size_t)v * (2 * F) + c * 4];
        float4 b4   = *(const float4*)&bias[c * 4];
        float4 o;
        o.x = self.x + ax * inv + b4.x;
        o.y = self.y + ay * inv + b4.y;
        o.z = self.z + az * inv + b4.z;
        o.w = self.w + aw * inv + b4.w;
        if (RELU) {
            o.x = fmaxf(o.x, 0.f); o.y = fmaxf(o.y, 0.f);
            o.z = fmaxf(o.z, 0.f); o.w = fmaxf(o.w, 0.f);
        }
        *(float4*)&out[(size_t)v * F + c * 4] = o;
    }
}

extern "C" void kernel_launch(void* const* d_in, const int* in_sizes, int n_in,
                              void* d_out, int out_size, void* d_ws, size_t ws_size,
                              hipStream_t stream) {
    const float* features = (const float*)d_in[0];
    const float* W_self1  = (const float*)d_in[1];
    const float* W_neigh1 = (const float*)d_in[2];
    const float* b1       = (const float*)d_in[3];
    const float* W_self2  = (const float*)d_in[4];
    const float* W_neigh2 = (const float*)d_in[5];
    const float* b2       = (const float*)d_in[6];
    const int*   src      = (const int*)d_in[7];
    const int*   dst      = (const int*)d_in[8];
    float*       out      = (float*)d_out;

    // Workspace layout:
    //   P : N*128 floats (25.6 MB) -- layer-1 concat transform; reused as Q later
    //   h : N*64  floats (12.8 MB) -- also aliased as brec (6.4 MB) during CSR build
    //   ints: counts, row_ptr (N each), bcursor (N_BUCKETS), csr_src (E), partials
    float* P = (float*)d_ws;
    float* Q = P;                                   // alias: P dead after layer-1 gather
    float* h = P + (size_t)N_NODES * 128;
    unsigned long long* brec = (unsigned long long*)h;  // alias: dead before h written
    int* counts   = (int*)(h + (size_t)N_NODES * 64);
    int* row_ptr  = counts + N_NODES;
    int* bcursor  = row_ptr + N_NODES;
    int* csr_src  = bcursor + N_BUCKETS;
    int* partials = csr_src + N_EDGES;

    // ---- CSR build (by dst) ----
    hipMemsetAsync(counts, 0, N_NODES * sizeof(int), stream);
    hist_kernel<<<(N_EDGES + 255) / 256, 256, 0, stream>>>(dst, counts);
    scan_blocks_kernel<<<SCAN_BLOCKS, 256, 0, stream>>>(counts, partials);
    scan_top_kernel<<<1, 256, 0, stream>>>(partials);
    scan_apply_kernel<<<SCAN_BLOCKS, 256, 0, stream>>>(counts, partials, row_ptr);
    bucket_cursor_init<<<(N_BUCKETS + 255) / 256, 256, 0, stream>>>(row_ptr, bcursor);
    bucket_append<<<(N_EDGES + 255) / 256, 256, 0, stream>>>(src, dst, bcursor, brec);
    bucket_fill<<<N_BUCKETS, 256, 0, stream>>>(row_ptr, brec, csr_src);

    const int gemm_blocks   = (N_NODES + 63) / 64;   // 782
    const int gather_blocks = (N_NODES + 3) / 4;     // 4 waves/block, 1 node/wave

    // ---- Layer 1: P = x @ [Ws1|Wn1]; h = relu(P_self + mean(P_neigh[src]) + b1) ----
    gemm_cat<128><<<gemm_blocks, 256, 0, stream>>>(features, W_self1, W_neigh1, P);
    gather_epilogue<64, true><<<gather_blocks, 256, 0, stream>>>(
        P, row_ptr, counts, csr_src, b1, h);

    // ---- Layer 2: Q = h @ [Ws2|Wn2]; out = Q_self + mean(Q_neigh[src]) + b2 ----
    gemm_cat<64><<<gemm_blocks, 256, 0, stream>>>(h, W_self2, W_neigh2, Q);
    gather_epilogue<32, false><<<gather_blocks, 256, 0, stream>>>(
        Q, row_ptr, counts, csr_src, b2, out);
}

// Round 5
// 248.931 us; speedup vs baseline: 1.6396x; 1.6396x over previous
//
#include <hip/hip_runtime.h>

#define N_NODES 50000
#define N_EDGES 800000
#define SCAN_BLOCKS 196            // ceil(50000/256)

typedef unsigned short ushort_t;

__device__ __forceinline__ float bf2f(ushort_t u) {
    return __uint_as_float(((unsigned int)u) << 16);
}
__device__ __forceinline__ ushort_t f2bf(float f) {   // round-to-nearest-even
    unsigned int x = __float_as_uint(f);
    return (ushort_t)((x + 0x7fffu + ((x >> 16) & 1u)) >> 16);
}

// ---------------- CSR build ----------------

__global__ __launch_bounds__(256)
void hist_kernel(const int* __restrict__ dst, int* __restrict__ counts) {
    int e = blockIdx.x * blockDim.x + threadIdx.x;
    if (e < N_EDGES) atomicAdd(&counts[dst[e]], 1);
}

__global__ __launch_bounds__(256)
void scan_blocks_kernel(const int* __restrict__ counts, int* __restrict__ partials) {
    __shared__ int buf[256];
    int i = blockIdx.x * 256 + threadIdx.x;
    buf[threadIdx.x] = (i < N_NODES) ? counts[i] : 0;
    __syncthreads();
    for (int off = 128; off > 0; off >>= 1) {
        if (threadIdx.x < off) buf[threadIdx.x] += buf[threadIdx.x + off];
        __syncthreads();
    }
    if (threadIdx.x == 0) partials[blockIdx.x] = buf[0];
}

// Parallel exclusive scan of SCAN_BLOCKS (<=256) partials in one block.
__global__ __launch_bounds__(256)
void scan_top_kernel(int* __restrict__ partials) {
    __shared__ int buf[256];
    int t = threadIdx.x;
    int v = (t < SCAN_BLOCKS) ? partials[t] : 0;
    buf[t] = v;
    __syncthreads();
    for (int off = 1; off < 256; off <<= 1) {
        int add = (t >= off) ? buf[t - off] : 0;
        __syncthreads();
        buf[t] += add;
        __syncthreads();
    }
    if (t < SCAN_BLOCKS) partials[t] = buf[t] - v;   // exclusive
}

__global__ __launch_bounds__(256)
void scan_apply_kernel(const int* __restrict__ counts, const int* __restrict__ offsets,
                       int* __restrict__ row_ptr, int* __restrict__ cursor) {
    __shared__ int buf[256];
    int t = threadIdx.x;
    int i = blockIdx.x * 256 + t;
    int v = (i < N_NODES) ? counts[i] : 0;
    buf[t] = v;
    __syncthreads();
    for (int off = 1; off < 256; off <<= 1) {
        int add = (t >= off) ? buf[t - off] : 0;
        __syncthreads();
        buf[t] += add;
        __syncthreads();
    }
    if (i < N_NODES) {
        int rp = offsets[blockIdx.x] + buf[t] - v;   // exclusive
        row_ptr[i] = rp;
        cursor[i]  = rp;
    }
}

// Node-level fill: 50k cursor addresses -> shallow atomic chains; write-amp bound (~50us).
__global__ __launch_bounds__(256)
void fill_kernel(const int* __restrict__ src, const int* __restrict__ dst,
                 int* __restrict__ cursor, int* __restrict__ csr_src) {
    int e = blockIdx.x * blockDim.x + threadIdx.x;
    if (e < N_EDGES) {
        int d = dst[e];
        int pos = atomicAdd(&cursor[d], 1);
        csr_src[pos] = src[e];
    }
}

// ---------------- Register-tiled fp32 GEMM: [Cself|Cn] = A[N,64] @ [B1|B2] ----------------
// F = total cols (2H). Self half (cols < H) stored fp32; neighbor half stored bf16 (RNE).
template <int F>
__global__ __launch_bounds__(256)
void gemm_cat(const float* __restrict__ A,
              const float* __restrict__ B1,   // [64, H]
              const float* __restrict__ B2,   // [64, H]
              float* __restrict__ Cself,      // [N, H] fp32
              ushort_t* __restrict__ Cn) {    // [N, H] bf16
    constexpr int H = F / 2;
    constexpr int HALVES = F / 64;          // 1 or 2
    __shared__ float As[64][68];            // transposed A tile, padded
    __shared__ float Bs[64][F];

    for (int i = threadIdx.x; i < 64 * H; i += 256) {
        int k = i / H, j = i % H;
        Bs[k][j]     = B1[i];
        Bs[k][j + H] = B2[i];
    }
    const int m0 = blockIdx.x * 64;
    {
        int mloc = threadIdx.x >> 4;          // 0..15
        int k4   = (threadIdx.x & 15) * 4;    // 0..60
#pragma unroll
        for (int it = 0; it < 4; ++it) {
            int m  = mloc + it * 16;
            int gm = m0 + m;
            float4 a = (gm < N_NODES) ? *(const float4*)&A[(size_t)gm * 64 + k4]
                                      : make_float4(0.f, 0.f, 0.f, 0.f);
            As[k4 + 0][m] = a.x; As[k4 + 1][m] = a.y;
            As[k4 + 2][m] = a.z; As[k4 + 3][m] = a.w;
        }
    }
    __syncthreads();

    const int tm  = ((threadIdx.x >> 4) & 3) * 4 + (threadIdx.x >> 6) * 16;  // 0..60
    const int tn4 = (threadIdx.x & 15) * 4;                                   // 0..60

    float acc[4][HALVES][4];
#pragma unroll
    for (int mi = 0; mi < 4; ++mi)
#pragma unroll
        for (int hh = 0; hh < HALVES; ++hh)
#pragma unroll
            for (int ni = 0; ni < 4; ++ni) acc[mi][hh][ni] = 0.f;

#pragma unroll 8
    for (int k = 0; k < 64; ++k) {
        float4 a = *(const float4*)&As[k][tm];
        float4 b[HALVES];
#pragma unroll
        for (int hh = 0; hh < HALVES; ++hh)
            b[hh] = *(const float4*)&Bs[k][tn4 + hh * 64];
        const float am[4] = {a.x, a.y, a.z, a.w};
#pragma unroll
        for (int mi = 0; mi < 4; ++mi) {
#pragma unroll
            for (int hh = 0; hh < HALVES; ++hh) {
                acc[mi][hh][0] += am[mi] * b[hh].x;
                acc[mi][hh][1] += am[mi] * b[hh].y;
                acc[mi][hh][2] += am[mi] * b[hh].z;
                acc[mi][hh][3] += am[mi] * b[hh].w;
            }
        }
    }

#pragma unroll
    for (int mi = 0; mi < 4; ++mi) {
        int gm = m0 + tm + mi;
        if (gm < N_NODES) {
#pragma unroll
            for (int hh = 0; hh < HALVES; ++hh) {
                int col = tn4 + hh * 64;
                if (col < H) {
                    *(float4*)&Cself[(size_t)gm * H + col] = *(float4*)&acc[mi][hh][0];
                } else {
                    ushort4 u;
                    u.x = f2bf(acc[mi][hh][0]);
                    u.y = f2bf(acc[mi][hh][1]);
                    u.z = f2bf(acc[mi][hh][2]);
                    u.w = f2bf(acc[mi][hh][3]);
                    *(ushort4*)&Cn[(size_t)gm * H + (col - H)] = u;
                }
            }
        }
    }
}

// ---------------- Gather mean (bf16 table) + fused epilogue ----------------
// out[v] = act( Cself[v] + mean_{u in N(v)} Cn[u] + bias )
// One wave per node; LPR = F/4 lanes per row (ushort4 each); R = 64/LPR rows in flight.
template <int F, bool RELU>
__global__ __launch_bounds__(256)
void gather_epilogue(const float* __restrict__ Tself,
                     const ushort_t* __restrict__ Tn,
                     const int* __restrict__ row_ptr, const int* __restrict__ counts,
                     const int* __restrict__ csr_src, const float* __restrict__ bias,
                     float* __restrict__ out) {
    constexpr int LPR = F / 4;
    constexpr int R   = 64 / LPR;
    int v = (blockIdx.x * blockDim.x + threadIdx.x) >> 6;   // node id
    int lane = threadIdx.x & 63;
    int r = lane / LPR;
    int c = lane % LPR;
    if (v >= N_NODES) return;
    int start = row_ptr[v];
    int cnt   = counts[v];

    float a0 = 0.f, a1 = 0.f, a2 = 0.f, a3 = 0.f;
    int t = r;
    for (; t + R < cnt; t += 2 * R) {
        int s0 = csr_src[start + t];
        int s1 = csr_src[start + t + R];
        ushort4 u0 = *(const ushort4*)&Tn[(size_t)s0 * F + c * 4];
        ushort4 u1 = *(const ushort4*)&Tn[(size_t)s1 * F + c * 4];
        a0 += bf2f(u0.x) + bf2f(u1.x);
        a1 += bf2f(u0.y) + bf2f(u1.y);
        a2 += bf2f(u0.z) + bf2f(u1.z);
        a3 += bf2f(u0.w) + bf2f(u1.w);
    }
    if (t < cnt) {
        int s = csr_src[start + t];
        ushort4 u = *(const ushort4*)&Tn[(size_t)s * F + c * 4];
        a0 += bf2f(u.x); a1 += bf2f(u.y); a2 += bf2f(u.z); a3 += bf2f(u.w);
    }
#pragma unroll
    for (int off = LPR; off < 64; off <<= 1) {
        a0 += __shfl_xor(a0, off);
        a1 += __shfl_xor(a1, off);
        a2 += __shfl_xor(a2, off);
        a3 += __shfl_xor(a3, off);
    }
    if (r == 0) {
        float inv = 1.0f / (float)max(cnt, 1);
        float4 self = *(const float4*)&Tself[(size_t)v * F + c * 4];
        float4 b4   = *(const float4*)&bias[c * 4];
        float4 o;
        o.x = self.x + a0 * inv + b4.x;
        o.y = self.y + a1 * inv + b4.y;
        o.z = self.z + a2 * inv + b4.z;
        o.w = self.w + a3 * inv + b4.w;
        if (RELU) {
            o.x = fmaxf(o.x, 0.f); o.y = fmaxf(o.y, 0.f);
            o.z = fmaxf(o.z, 0.f); o.w = fmaxf(o.w, 0.f);
        }
        *(float4*)&out[(size_t)v * F + c * 4] = o;
    }
}

extern "C" void kernel_launch(void* const* d_in, const int* in_sizes, int n_in,
                              void* d_out, int out_size, void* d_ws, size_t ws_size,
                              hipStream_t stream) {
    const float* features = (const float*)d_in[0];
    const float* W_self1  = (const float*)d_in[1];
    const float* W_neigh1 = (const float*)d_in[2];
    const float* b1       = (const float*)d_in[3];
    const float* W_self2  = (const float*)d_in[4];
    const float* W_neigh2 = (const float*)d_in[5];
    const float* b2       = (const float*)d_in[6];
    const int*   src      = (const int*)d_in[7];
    const int*   dst      = (const int*)d_in[8];
    float*       out      = (float*)d_out;

    // Workspace:
    //   Tself1 : N*64 f32 (12.8 MB)  -- layer-1 self transform (reused as Tself2, N*32)
    //   Tn1    : N*64 bf16 (6.4 MB)  -- layer-1 neighbor transform (reused as Tn2, N*32)
    //   h      : N*64 f32 (12.8 MB)
    //   ints   : counts, row_ptr, cursor (N each), csr_src (E), partials
    float*    Tself1 = (float*)d_ws;
    ushort_t* Tn1    = (ushort_t*)(Tself1 + (size_t)N_NODES * 64);
    float*    h      = (float*)(Tn1 + (size_t)N_NODES * 64);
    int* counts   = (int*)(h + (size_t)N_NODES * 64);
    int* row_ptr  = counts + N_NODES;
    int* cursor   = row_ptr + N_NODES;
    int* csr_src  = cursor + N_NODES;
    int* partials = csr_src + N_EDGES;

    float*    Tself2 = Tself1;   // alias: layer-1 tables dead after first gather
    ushort_t* Tn2    = Tn1;

    // ---- CSR build (by dst) ----
    hipMemsetAsync(counts, 0, N_NODES * sizeof(int), stream);
    hist_kernel<<<(N_EDGES + 255) / 256, 256, 0, stream>>>(dst, counts);
    scan_blocks_kernel<<<SCAN_BLOCKS, 256, 0, stream>>>(counts, partials);
    scan_top_kernel<<<1, 256, 0, stream>>>(partials);
    scan_apply_kernel<<<SCAN_BLOCKS, 256, 0, stream>>>(counts, partials, row_ptr, cursor);
    fill_kernel<<<(N_EDGES + 255) / 256, 256, 0, stream>>>(src, dst, cursor, csr_src);

    const int gemm_blocks   = (N_NODES + 63) / 64;   // 782
    const int gather_blocks = (N_NODES + 3) / 4;     // 4 waves/block, 1 node/wave

    // ---- Layer 1 ----
    gemm_cat<128><<<gemm_blocks, 256, 0, stream>>>(features, W_self1, W_neigh1, Tself1, Tn1);
    gather_epilogue<64, true><<<gather_blocks, 256, 0, stream>>>(
        Tself1, Tn1, row_ptr, counts, csr_src, b1, h);

    // ---- Layer 2 ----
    gemm_cat<64><<<gemm_blocks, 256, 0, stream>>>(h, W_self2, W_neigh2, Tself2, Tn2);
    gather_epilogue<32, false><<<gather_blocks, 256, 0, stream>>>(
        Tself2, Tn2, row_ptr, counts, csr_src, b2, out);
}

// Round 6
// 203.656 us; speedup vs baseline: 2.0041x; 1.2223x over previous
//
#include <hip/hip_runtime.h>

#define N_NODES 50000
#define N_EDGES 800000
#define NB 196                 // buckets of 256 nodes: ceil(50000/256)
#define PBLOCKS 128            // partition blocks
#define CHUNK 6250             // N_EDGES / PBLOCKS (exact)
#define SCAN_N (NB * PBLOCKS)  // 25088

typedef unsigned short ushort_t;

__device__ __forceinline__ float bf2f(ushort_t u) {
    return __uint_as_float(((unsigned int)u) << 16);
}
__device__ __forceinline__ ushort_t f2bf(float f) {   // round-to-nearest-even
    unsigned int x = __float_as_uint(f);
    return (ushort_t)((x + 0x7fffu + ((x >> 16) & 1u)) >> 16);
}

// ---------------- CSR build: atomic-free radix partition ----------------

// Pass A: per-block LDS histogram over NB buckets -> blocktot[bin*PBLOCKS+block]
__global__ __launch_bounds__(256)
void part_count(const int* __restrict__ dst, int* __restrict__ blocktot) {
    __shared__ int hist[NB];
    for (int i = threadIdx.x; i < NB; i += 256) hist[i] = 0;
    __syncthreads();
    const int e0 = blockIdx.x * CHUNK;
    const int e1 = e0 + CHUNK;
    for (int e = e0 + (int)threadIdx.x; e < e1; e += 256)
        atomicAdd(&hist[dst[e] >> 8], 1);
    __syncthreads();
    for (int i = threadIdx.x; i < NB; i += 256)
        blocktot[i * PBLOCKS + blockIdx.x] = hist[i];
}

// Pass B: exclusive scan of SCAN_N values (bin-major) in one block.
__global__ __launch_bounds__(1024)
void part_scan(const int* __restrict__ blocktot, int* __restrict__ blockstart) {
    __shared__ int psum[1024];
    constexpr int PER = (SCAN_N + 1023) / 1024;   // 25
    const int t = threadIdx.x;
    const int base = t * PER;
    int local[PER];
    int s = 0;
#pragma unroll
    for (int i = 0; i < PER; ++i) {
        int idx = base + i;
        int v = (idx < SCAN_N) ? blocktot[idx] : 0;
        local[i] = s;
        s += v;
    }
    psum[t] = s;
    __syncthreads();
    for (int off = 1; off < 1024; off <<= 1) {
        int add = (t >= off) ? psum[t - off] : 0;
        __syncthreads();
        psum[t] += add;
        __syncthreads();
    }
    const int tbase = psum[t] - s;   // exclusive prefix of this thread
#pragma unroll
    for (int i = 0; i < PER; ++i) {
        int idx = base + i;
        if (idx < SCAN_N) blockstart[idx] = tbase + local[i];
    }
    if (t == 1023) blockstart[SCAN_N] = psum[1023];   // == N_EDGES
}

// Pass C: write packed records (d_local:8 | s:16) into reserved per-(bin,block) streams.
__global__ __launch_bounds__(256)
void part_write(const int* __restrict__ src, const int* __restrict__ dst,
                const int* __restrict__ blockstart, unsigned int* __restrict__ brec) {
    __shared__ int cur[NB];
    for (int i = threadIdx.x; i < NB; i += 256)
        cur[i] = blockstart[i * PBLOCKS + blockIdx.x];
    __syncthreads();
    const int e0 = blockIdx.x * CHUNK;
    const int e1 = e0 + CHUNK;
    for (int e = e0 + (int)threadIdx.x; e < e1; e += 256) {
        int d = dst[e];
        int s = src[e];
        int pos = atomicAdd(&cur[d >> 8], 1);
        brec[pos] = ((unsigned int)(d & 255) << 16) | (unsigned int)s;
    }
}

// Pass D: one block per bucket. Per-node counts -> scan -> row_ptr, then
// window-confined scatter into csr_src (single block/XCD => L2 merges writes).
__global__ __launch_bounds__(256)
void bucket_fill(const int* __restrict__ blockstart,
                 const unsigned int* __restrict__ brec,
                 int* __restrict__ csr_src, int* __restrict__ row_ptr) {
    __shared__ int cnt[256];
    __shared__ int cur[256];
    const int b = blockIdx.x;
    const int node0 = b * 256;
    const int w0 = blockstart[b * PBLOCKS];
    const int w1 = blockstart[(b + 1) * PBLOCKS];
    const int t = threadIdx.x;
    cnt[t] = 0;
    __syncthreads();
    for (int i = w0 + t; i < w1; i += 256)
        atomicAdd(&cnt[brec[i] >> 16], 1);
    __syncthreads();
    const int v = cnt[t];
    cur[t] = v;
    __syncthreads();
    for (int off = 1; off < 256; off <<= 1) {
        int add = (t >= off) ? cur[t - off] : 0;
        __syncthreads();
        cur[t] += add;
        __syncthreads();
    }
    const int excl = cur[t] - v;
    const int node = node0 + t;
    if (node <= N_NODES) row_ptr[node] = w0 + excl;   // includes sentinel at node==N
    __syncthreads();
    cur[t] = w0 + excl;
    __syncthreads();
    for (int i = w0 + t; i < w1; i += 256) {
        unsigned int r = brec[i];
        int pos = atomicAdd(&cur[r >> 16], 1);
        csr_src[pos] = (int)(r & 0xffffu);
    }
}

// ---------------- Register-tiled fp32 GEMM: [Cself|Cn] = A[N,64] @ [B1|B2] ----------------
// Self half stored fp32; neighbor half stored bf16 (RNE) for cheap gathers.
template <int F>
__global__ __launch_bounds__(256)
void gemm_cat(const float* __restrict__ A,
              const float* __restrict__ B1,   // [64, H]
              const float* __restrict__ B2,   // [64, H]
              float* __restrict__ Cself,      // [N, H] fp32
              ushort_t* __restrict__ Cn) {    // [N, H] bf16
    constexpr int H = F / 2;
    constexpr int HALVES = F / 64;          // 1 or 2
    __shared__ float As[64][68];            // transposed A tile, padded
    __shared__ float Bs[64][F];

    for (int i = threadIdx.x; i < 64 * H; i += 256) {
        int k = i / H, j = i % H;
        Bs[k][j]     = B1[i];
        Bs[k][j + H] = B2[i];
    }
    const int m0 = blockIdx.x * 64;
    {
        int mloc = threadIdx.x >> 4;          // 0..15
        int k4   = (threadIdx.x & 15) * 4;    // 0..60
#pragma unroll
        for (int it = 0; it < 4; ++it) {
            int m  = mloc + it * 16;
            int gm = m0 + m;
            float4 a = (gm < N_NODES) ? *(const float4*)&A[(size_t)gm * 64 + k4]
                                      : make_float4(0.f, 0.f, 0.f, 0.f);
            As[k4 + 0][m] = a.x; As[k4 + 1][m] = a.y;
            As[k4 + 2][m] = a.z; As[k4 + 3][m] = a.w;
        }
    }
    __syncthreads();

    const int tm  = ((threadIdx.x >> 4) & 3) * 4 + (threadIdx.x >> 6) * 16;  // 0..60
    const int tn4 = (threadIdx.x & 15) * 4;                                   // 0..60

    float acc[4][HALVES][4];
#pragma unroll
    for (int mi = 0; mi < 4; ++mi)
#pragma unroll
        for (int hh = 0; hh < HALVES; ++hh)
#pragma unroll
            for (int ni = 0; ni < 4; ++ni) acc[mi][hh][ni] = 0.f;

#pragma unroll 8
    for (int k = 0; k < 64; ++k) {
        float4 a = *(const float4*)&As[k][tm];
        float4 b[HALVES];
#pragma unroll
        for (int hh = 0; hh < HALVES; ++hh)
            b[hh] = *(const float4*)&Bs[k][tn4 + hh * 64];
        const float am[4] = {a.x, a.y, a.z, a.w};
#pragma unroll
        for (int mi = 0; mi < 4; ++mi) {
#pragma unroll
            for (int hh = 0; hh < HALVES; ++hh) {
                acc[mi][hh][0] += am[mi] * b[hh].x;
                acc[mi][hh][1] += am[mi] * b[hh].y;
                acc[mi][hh][2] += am[mi] * b[hh].z;
                acc[mi][hh][3] += am[mi] * b[hh].w;
            }
        }
    }

#pragma unroll
    for (int mi = 0; mi < 4; ++mi) {
        int gm = m0 + tm + mi;
        if (gm < N_NODES) {
#pragma unroll
            for (int hh = 0; hh < HALVES; ++hh) {
                int col = tn4 + hh * 64;
                if (col < H) {
                    *(float4*)&Cself[(size_t)gm * H + col] = *(float4*)&acc[mi][hh][0];
                } else {
                    ushort4 u;
                    u.x = f2bf(acc[mi][hh][0]);
                    u.y = f2bf(acc[mi][hh][1]);
                    u.z = f2bf(acc[mi][hh][2]);
                    u.w = f2bf(acc[mi][hh][3]);
                    *(ushort4*)&Cn[(size_t)gm * H + (col - H)] = u;
                }
            }
        }
    }
}

// ---------------- Gather mean (bf16 table) + fused epilogue ----------------
// out[v] = act( Cself[v] + mean_{u in N(v)} Cn[u] + bias )
template <int F, bool RELU>
__global__ __launch_bounds__(256)
void gather_epilogue(const float* __restrict__ Tself,
                     const ushort_t* __restrict__ Tn,
                     const int* __restrict__ row_ptr,
                     const int* __restrict__ csr_src, const float* __restrict__ bias,
                     float* __restrict__ out) {
    constexpr int LPR = F / 4;
    constexpr int R   = 64 / LPR;
    int v = (blockIdx.x * blockDim.x + threadIdx.x) >> 6;   // node id
    int lane = threadIdx.x & 63;
    int r = lane / LPR;
    int c = lane % LPR;
    if (v >= N_NODES) return;
    int start = row_ptr[v];
    int cnt   = row_ptr[v + 1] - start;

    float a0 = 0.f, a1 = 0.f, a2 = 0.f, a3 = 0.f;
    int t = r;
    for (; t + R < cnt; t += 2 * R) {
        int s0 = csr_src[start + t];
        int s1 = csr_src[start + t + R];
        ushort4 u0 = *(const ushort4*)&Tn[(size_t)s0 * F + c * 4];
        ushort4 u1 = *(const ushort4*)&Tn[(size_t)s1 * F + c * 4];
        a0 += bf2f(u0.x) + bf2f(u1.x);
        a1 += bf2f(u0.y) + bf2f(u1.y);
        a2 += bf2f(u0.z) + bf2f(u1.z);
        a3 += bf2f(u0.w) + bf2f(u1.w);
    }
    if (t < cnt) {
        int s = csr_src[start + t];
        ushort4 u = *(const ushort4*)&Tn[(size_t)s * F + c * 4];
        a0 += bf2f(u.x); a1 += bf2f(u.y); a2 += bf2f(u.z); a3 += bf2f(u.w);
    }
#pragma unroll
    for (int off = LPR; off < 64; off <<= 1) {
        a0 += __shfl_xor(a0, off);
        a1 += __shfl_xor(a1, off);
        a2 += __shfl_xor(a2, off);
        a3 += __shfl_xor(a3, off);
    }
    if (r == 0) {
        float inv = 1.0f / (float)max(cnt, 1);
        float4 self = *(const float4*)&Tself[(size_t)v * F + c * 4];
        float4 b4   = *(const float4*)&bias[c * 4];
        float4 o;
        o.x = self.x + a0 * inv + b4.x;
        o.y = self.y + a1 * inv + b4.y;
        o.z = self.z + a2 * inv + b4.z;
        o.w = self.w + a3 * inv + b4.w;
        if (RELU) {
            o.x = fmaxf(o.x, 0.f); o.y = fmaxf(o.y, 0.f);
            o.z = fmaxf(o.z, 0.f); o.w = fmaxf(o.w, 0.f);
        }
        *(float4*)&out[(size_t)v * F + c * 4] = o;
    }
}

extern "C" void kernel_launch(void* const* d_in, const int* in_sizes, int n_in,
                              void* d_out, int out_size, void* d_ws, size_t ws_size,
                              hipStream_t stream) {
    const float* features = (const float*)d_in[0];
    const float* W_self1  = (const float*)d_in[1];
    const float* W_neigh1 = (const float*)d_in[2];
    const float* b1       = (const float*)d_in[3];
    const float* W_self2  = (const float*)d_in[4];
    const float* W_neigh2 = (const float*)d_in[5];
    const float* b2       = (const float*)d_in[6];
    const int*   src      = (const int*)d_in[7];
    const int*   dst      = (const int*)d_in[8];
    float*       out      = (float*)d_out;

    // Workspace:
    //   Tself1 : N*64 f32 (12.8 MB)  (reused as Tself2 N*32)
    //   Tn1    : N*64 bf16 (6.4 MB)  (reused as Tn2 N*32)
    //   h      : N*64 f32 (12.8 MB)
    //   row_ptr: N+1 ints; csr_src: E ints; brec: E uints;
    //   blocktot/blockstart: SCAN_N / SCAN_N+1 ints
    float*    Tself1 = (float*)d_ws;
    ushort_t* Tn1    = (ushort_t*)(Tself1 + (size_t)N_NODES * 64);
    float*    h      = (float*)(Tn1 + (size_t)N_NODES * 64);
    int* row_ptr     = (int*)(h + (size_t)N_NODES * 64);
    int* csr_src     = row_ptr + (N_NODES + 1);
    unsigned int* brec = (unsigned int*)(csr_src + N_EDGES);
    int* blocktot    = (int*)(brec + N_EDGES);
    int* blockstart  = blocktot + SCAN_N;

    float*    Tself2 = Tself1;   // alias: layer-1 tables dead after first gather
    ushort_t* Tn2    = Tn1;

    // ---- CSR build (by dst), atomic-free partition ----
    part_count<<<PBLOCKS, 256, 0, stream>>>(dst, blocktot);
    part_scan<<<1, 1024, 0, stream>>>(blocktot, blockstart);
    part_write<<<PBLOCKS, 256, 0, stream>>>(src, dst, blockstart, brec);
    bucket_fill<<<NB, 256, 0, stream>>>(blockstart, brec, csr_src, row_ptr);

    const int gemm_blocks   = (N_NODES + 63) / 64;   // 782
    const int gather_blocks = (N_NODES + 3) / 4;     // 4 waves/block, 1 node/wave

    // ---- Layer 1 ----
    gemm_cat<128><<<gemm_blocks, 256, 0, stream>>>(features, W_self1, W_neigh1, Tself1, Tn1);
    gather_epilogue<64, true><<<gather_blocks, 256, 0, stream>>>(
        Tself1, Tn1, row_ptr, csr_src, b1, h);

    // ---- Layer 2 ----
    gemm_cat<64><<<gemm_blocks, 256, 0, stream>>>(h, W_self2, W_neigh2, Tself2, Tn2);
    gather_epilogue<32, false><<<gather_blocks, 256, 0, stream>>>(
        Tself2, Tn2, row_ptr, csr_src, b2, out);
}